// Round 1
// 543.597 us; speedup vs baseline: 1.0240x; 1.0240x over previous
//
#include <hip/hip_runtime.h>
#include <math.h>

#define B 64
#define N 1024
#define F 256

// Output layout (floats), concatenated in reference return order:
//   mx [B,F] | nodes [B,N,F] | adj [B,N,N] | num_nodes+1 [B]
#define OUT_MX    0
#define OUT_NODES (B * F)                        // 16384
#define OUT_ADJ   (OUT_NODES + B * N * F)        // 16793600
#define OUT_NN    (OUT_ADJ + B * N * N)          // 83902464

#define NODES_BLOCKS (B * 16)                    // 1024: one block = 64-row slice
#define ADJ_BLOCKS   (B * N / 4)                 // 16384: one block = 4 adj rows

typedef float f4 __attribute__((ext_vector_type(4)));

// ---------------------------------------------------------------------------
// Fused main kernel.
// Branch A (blk < NODES_BLOCKS): write updated nodes (wrap-roll + scatter x)
//   for a 64-row slice of batch b, and simultaneously accumulate the partial
//   reduction t_partial = sum_m adj[b][nn][m] * nodes_new[b][m][:] for those
//   rows. Partials land in ws (no atomics, no zero-init needed).
// Branch B: pure adj update copy, 4 rows of 1024 floats per block, float4.
// All once-touched streams use non-temporal loads/stores to keep L2 for the
// reused data (x, W, num_nodes, partial).
__global__ __launch_bounds__(256) void k_main(
        const float* __restrict__ x,
        const float* __restrict__ nodes,
        const float* __restrict__ adj,
        const int* __restrict__ num_nodes,
        float* __restrict__ out,
        float* __restrict__ partial) {
    __shared__ float arow[64];
    int blk = blockIdx.x;
    int t = threadIdx.x;

    if (blk < NODES_BLOCKS) {
        int b = blk >> 4;
        int s = blk & 15;
        int m0 = s << 6;                       // first row of the 64-row slice
        int nn_in = num_nodes[b];
        bool wrapped = (nn_in == N);
        int nn = wrapped ? (N - 1) : nn_in;
        // Stage the adj row segment (original adj row nn is unchanged by the
        // update when !wrapped; when wrapped the updated row is all-zero).
        if (t < 64)
            arow[t] = wrapped ? 0.0f
                              : adj[((long)b * N + nn) * N + m0 + t];
        __syncthreads();

        int g   = t >> 6;                      // wave id 0..3 (row group)
        int f4i = (t & 63) << 2;               // feature column 0,4,...,252
        const float* xrow   = x + (long)b * F;
        const float* innode = nodes + (long)b * N * F;
        float* onode = out + OUT_NODES + ((long)b * N + m0) * F;
        f4 acc = (f4)0.0f;
        #pragma unroll
        for (int it = 0; it < 16; ++it) {
            int r = (it << 2) + g;             // row within slice, wave-uniform
            int row = m0 + r;
            f4 v;
            if (row == nn) {
                v = *(const f4*)(xrow + f4i);
            } else {
                // wrapped: row < N-1 here (row==N-1 implies row==nn)
                int srow = wrapped ? (row + 1) : row;
                v = __builtin_nontemporal_load(
                        (const f4*)(innode + (long)srow * F + f4i));
            }
            __builtin_nontemporal_store(v, (f4*)(onode + (long)r * F + f4i));
            float a = arow[r];                 // wave-uniform LDS broadcast
            acc += a * v;
        }
        // partial slot p = b*64 + s*4 + g  (64 partials per batch)
        *(f4*)(partial + ((long)(b << 6) + (s << 2) + g) * F + f4i) = acc;
    } else {
        long rb = (long)(blk - NODES_BLOCKS) << 2;   // first (b,i) row
        int j = t << 2;                              // column 0,4,...,1020
        #pragma unroll
        for (int k = 0; k < 4; ++k) {
            long bi = rb + k;
            int b = (int)(bi >> 10);
            int i = (int)(bi & (N - 1));
            bool wrapped = (num_nodes[b] == N);
            const float* base = adj + (long)b * N * N;
            f4 v;
            if (!wrapped) {
                v = __builtin_nontemporal_load(
                        (const f4*)(base + (long)i * N + j));
            } else if (i >= N - 1) {
                v = (f4)0.0f;
            } else {
                const float* r2 = base + (long)(i + 1) * N;
                v.x = (j + 0 < N - 1) ? r2[j + 1] : 0.f;
                v.y = (j + 1 < N - 1) ? r2[j + 2] : 0.f;
                v.z = (j + 2 < N - 1) ? r2[j + 3] : 0.f;
                v.w = (j + 3 < N - 1) ? r2[j + 4] : 0.f;
            }
            __builtin_nontemporal_store(v, (f4*)(out + OUT_ADJ + bi * N + j));
        }
    }
}

// ---------------------------------------------------------------------------
// Finalize: t[b,f] = sum of 64 partials; mx = tanh(t @ W); num_nodes+1.
// 1024 threads: both the 64-deep partial reduction and the 256-deep dot are
// split 4-way (q = t>>8) to cut the serial chains, combined through LDS.
__global__ __launch_bounds__(1024) void k_final(
        const float* __restrict__ partial,
        const float* __restrict__ W,
        const int* __restrict__ num_nodes,
        float* __restrict__ out) {
    int b = blockIdx.x;
    int t = threadIdx.x;                       // 0..1023
    int f = t & 255;
    int q = t >> 8;                            // 0..3
    __shared__ float red[4][F];
    __shared__ float tl[F];

    // phase 1: t[f] = sum_k partial[b][k][f], k split 4-way
    float s = 0.0f;
    const float* p = partial + ((long)(b << 6) + (q << 4)) * F + f;
    #pragma unroll
    for (int k = 0; k < 16; ++k)
        s += p[(long)k * F];
    red[q][f] = s;
    __syncthreads();
    if (t < F)
        tl[t] = red[0][t] + red[1][t] + red[2][t] + red[3][t];
    __syncthreads();

    // phase 2: mx[f] = tanh(sum_fp t[fp] * W[fp][f]), fp split 4-way
    float acc = 0.0f;
    const float* Wc = W + (q << 6) * F + f;
    #pragma unroll 8
    for (int i = 0; i < 64; ++i)
        acc += tl[(q << 6) + i] * Wc[(long)i * F];   // tl: uniform broadcast
    red[q][f] = acc;
    __syncthreads();
    if (t < F)
        out[OUT_MX + b * F + t] =
            tanhf(red[0][t] + red[1][t] + red[2][t] + red[3][t]);
    if (t == 0) {
        int nn_in = num_nodes[b];
        int nn = (nn_in == N) ? (N - 1) : nn_in;
        out[OUT_NN + b] = (float)(nn + 1);
    }
}

// ---------------------------------------------------------------------------
extern "C" void kernel_launch(void* const* d_in, const int* in_sizes, int n_in,
                              void* d_out, int out_size, void* d_ws, size_t ws_size,
                              hipStream_t stream) {
    const float* x         = (const float*)d_in[0];
    const float* nodes     = (const float*)d_in[1];
    const float* adj       = (const float*)d_in[2];
    const int*   num_nodes = (const int*)d_in[3];
    const float* W         = (const float*)d_in[4];
    float* out     = (float*)d_out;
    float* partial = (float*)d_ws;             // B*64*F floats = 4 MB

    hipLaunchKernelGGL(k_main, dim3(NODES_BLOCKS + ADJ_BLOCKS), dim3(256), 0,
                       stream, x, nodes, adj, num_nodes, out, partial);
    hipLaunchKernelGGL(k_final, dim3(B), dim3(1024), 0, stream,
                       partial, W, num_nodes, out);
}